// Round 14
// baseline (262.528 us; speedup 1.0000x reference)
//
#include <hip/hip_runtime.h>

// VQ-VAE vector quantize + losses, MI355X.
// T=8192 rows, N_E=16384 codes, D=32.
// R14: R13 minus the straggler round. R13's k_tail grid of 1056 (32 merge +
//      1024 pass2) cost a 5th dispatch round at ~3% utilization (+24us) --
//      grids must be exact multiples of resident blocks (also seen R8).
//      Now: k_tail = exactly 1024 uniform blocks; merge/refine/output is
//      distributed 8 rows/block as a short uniform phase (16-lane butterfly
//      top-2 merge + lane-0 broadcast, shuffle-reduce refine dots).
//      Verified R13 pieces kept: ses2~=NS2F fold, sc2 self-compute in LDS,
//      last-block final, prep-zeroed accumulators. 3 launches.

#define N_E 16384
#define ED 32
#define T 8192
#define NS1 16      // pass-1 code splits (1024 codes each)
#define RS2 8       // pass-2 row splits  (1024 rows each)
#define NBLK_F (128 * RS2)        // fused tail blocks: exactly 1024

#define K2 288.53900817779268f    // 200 * log2(e)
#define NS2F -144.26950408889634f // -100 * log2(e)
#define LN2 0.6931471805599453f

typedef __attribute__((ext_vector_type(8))) short s16x8;
typedef __attribute__((ext_vector_type(4))) float f32x4;

__device__ __forceinline__ float fexp2(float x) { return __builtin_amdgcn_exp2f(x); }
__device__ __forceinline__ float flog2(float x) { return __builtin_amdgcn_logf(x); }
__device__ __forceinline__ float fmed3(float a, float b, float c) {
  return __builtin_amdgcn_fmed3f(a, b, c);
}

__device__ __forceinline__ unsigned short f2bf(float x) {
  unsigned u = __float_as_uint(x);
  unsigned r = (u + 0x7FFFu + ((u >> 16) & 1u)) >> 16;
  return (unsigned short)r;
}
__device__ __forceinline__ float bf2f(unsigned short h) {
  return __uint_as_float(((unsigned)h) << 16);
}

// split 8 floats (scaled by sc) of row `row`, group g into hi/lo bf16 frags,
// stored TILE-MAJOR: dst[tile*128 + g*16 + c] (hi), +64 (lo); s16x8 units.
__device__ __forceinline__ void split_store_t(short* __restrict__ base,
    int row, int g, float4 va, float4 vb, float sc) {
  float f[8] = { va.x * sc, va.y * sc, va.z * sc, va.w * sc,
                 vb.x * sc, vb.y * sc, vb.z * sc, vb.w * sc };
  s16x8 H, L;
#pragma unroll
  for (int e = 0; e < 8; ++e) {
    unsigned short h = f2bf(f[e]);
    H[e] = (short)h;
    L[e] = (short)f2bf(f[e] - bf2f(h));
  }
  s16x8* p = (s16x8*)base;
  const int tile = row >> 4, c = row & 15;
  p[tile * 128 + g * 16 + c] = H;
  p[tile * 128 + 64 + g * 16 + c] = L;
}

// --- prep: blocks 0..63 emb rows; 64..95 z transpose; 96..160 zero avg/scal ---
__global__ __launch_bounds__(256) void k_prep(const float* __restrict__ emb,
    const float* __restrict__ z, float* __restrict__ embn,
    float* __restrict__ ses2, float* __restrict__ zf, float* __restrict__ a02,
    short* __restrict__ ehl, short* __restrict__ zhl, float* __restrict__ avg,
    float* __restrict__ scal) {
  if (blockIdx.x < 64) {
    int n = blockIdx.x * 256 + threadIdx.x;
    const float4* r4 = (const float4*)(emb + (size_t)n * ED);
    float4 v[8]; float s = 0.f;
#pragma unroll
    for (int j = 0; j < 8; ++j) {
      v[j] = r4[j];
      s = fmaf(v[j].x, v[j].x, s); s = fmaf(v[j].y, v[j].y, s);
      s = fmaf(v[j].z, v[j].z, s); s = fmaf(v[j].w, v[j].w, s);
    }
    float inv = 1.0f / fmaxf(sqrtf(s), 1e-12f);
    float s2 = 0.f;
    float4* o4 = (float4*)(embn + (size_t)n * ED);
#pragma unroll
    for (int j = 0; j < 8; ++j) {
      float4 w; w.x = v[j].x * inv; w.y = v[j].y * inv;
      w.z = v[j].z * inv; w.w = v[j].w * inv;
      o4[j] = w; v[j] = w;
      s2 = fmaf(w.x, w.x, s2); s2 = fmaf(w.y, w.y, s2);
      s2 = fmaf(w.z, w.z, s2); s2 = fmaf(w.w, w.w, s2);
    }
    ses2[n] = NS2F * s2;               // true value, for the exact refine
#pragma unroll
    for (int g = 0; g < 4; ++g)
      split_store_t(ehl, n, g, v[2 * g], v[2 * g + 1], 1.0f);
  } else if (blockIdx.x < 96) {
    int t = (blockIdx.x - 64) * 256 + threadIdx.x;
    int b = t >> 8, hw = t & 255;
    const float* base = z + (size_t)b * (ED * 256) + hw;
    float4 v[8]; float s = 0.f;
#pragma unroll
    for (int j = 0; j < 8; ++j) {
      float4 w;
      w.x = base[(4 * j + 0) * 256]; w.y = base[(4 * j + 1) * 256];
      w.z = base[(4 * j + 2) * 256]; w.w = base[(4 * j + 3) * 256];
      v[j] = w;
      s = fmaf(w.x, w.x, s); s = fmaf(w.y, w.y, s);
      s = fmaf(w.z, w.z, s); s = fmaf(w.w, w.w, s);
    }
    float inv = 1.0f / fmaxf(sqrtf(s), 1e-12f);
    float s2 = 0.f;
    float4* o4 = (float4*)(zf + (size_t)t * ED);
#pragma unroll
    for (int j = 0; j < 8; ++j) {
      float4 w; w.x = v[j].x * inv; w.y = v[j].y * inv;
      w.z = v[j].z * inv; w.w = v[j].w * inv;
      o4[j] = w; v[j] = w;
      s2 = fmaf(w.x, w.x, s2); s2 = fmaf(w.y, w.y, s2);
      s2 = fmaf(w.z, w.z, s2); s2 = fmaf(w.w, w.w, s2);
    }
    a02[t] = NS2F * s2;
#pragma unroll
    for (int g = 0; g < 4; ++g)
      split_store_t(zhl, t, g, v[2 * g], v[2 * g + 1], K2);
  } else if (blockIdx.x < 160) {
    avg[(blockIdx.x - 96) * 256 + threadIdx.x] = 0.f;
  } else {
    if (threadIdx.x < 4) scal[threadIdx.x] = 0.f;  // [0]=sampE [1]=vq [2]=cnt
  }
}

// --- pass 1: wave owns 32 rows, sweeps a 1024-code split in 16-code tiles.
//     C-bias = a02 + 80 + NS2F (ses2 folded); fb = acc. Top-2 via
//     mantissa-packed keys (tile idx in low 6 bits; med3+max only). ---
__global__ __launch_bounds__(256, 4) void k_pass1(
    const short* __restrict__ ehl, const short* __restrict__ zhl,
    const float* __restrict__ a02, float* __restrict__ pm1,
    float* __restrict__ pm2, float* __restrict__ pZ,
    int* __restrict__ pi1, int* __restrict__ pi2) {
  const int lane = threadIdx.x & 63, wv = threadIdx.x >> 6;
  const int q = lane >> 4, c = lane & 15;
  const int rowbase = blockIdx.x * 128 + wv * 32;
  const int nb0 = blockIdx.y * (N_E / NS1);
  const int NT = (N_E / NS1) / 16;  // 64

  const s16x8* zg = (const s16x8*)zhl;
  const int atile = rowbase >> 4;
  s16x8 ah0 = zg[atile * 128 + lane],       al0 = zg[atile * 128 + 64 + lane];
  s16x8 ah1 = zg[(atile + 1) * 128 + lane], al1 = zg[(atile + 1) * 128 + 64 + lane];

  f32x4 bias0, bias1;
#pragma unroll
  for (int r = 0; r < 4; ++r) {
    bias0[r] = a02[rowbase + q * 4 + r] + (80.0f + NS2F);
    bias1[r] = a02[rowbase + 16 + q * 4 + r] + (80.0f + NS2F);
  }

  float m1[8], m2[8], Zs[8];
#pragma unroll
  for (int k = 0; k < 8; ++k) { m1[k] = -1e30f; m2[k] = -1e30f; Zs[k] = 0.f; }

  const s16x8* eg = (const s16x8*)ehl;
  const int btile0 = nb0 >> 4;
  s16x8 bh = eg[btile0 * 128 + lane], bl = eg[btile0 * 128 + 64 + lane];

  for (int tile = 0; tile < NT; ++tile) {
    const int nx = (tile + 1 < NT) ? tile + 1 : tile;     // uniform
    const int nidx = (btile0 + nx) * 128 + lane;
    s16x8 nh = eg[nidx], nl = eg[nidx + 64];              // prefetch (2x1KB)

    f32x4 acc0 = __builtin_amdgcn_mfma_f32_16x16x32_bf16(ah0, bh, bias0, 0, 0, 0);
    f32x4 acc1 = __builtin_amdgcn_mfma_f32_16x16x32_bf16(ah1, bh, bias1, 0, 0, 0);
    acc0 = __builtin_amdgcn_mfma_f32_16x16x32_bf16(al0, bh, acc0, 0, 0, 0);
    acc1 = __builtin_amdgcn_mfma_f32_16x16x32_bf16(al1, bh, acc1, 0, 0, 0);
    acc0 = __builtin_amdgcn_mfma_f32_16x16x32_bf16(ah0, bl, acc0, 0, 0, 0);
    acc1 = __builtin_amdgcn_mfma_f32_16x16x32_bf16(ah1, bl, acc1, 0, 0, 0);

    const unsigned tu = (unsigned)tile;                   // uniform 6-bit idx
#pragma unroll
    for (int g = 0; g < 2; ++g) {
#pragma unroll
      for (int r = 0; r < 4; ++r) {
        const int k = g * 4 + r;
        float fb = (g == 0) ? acc0[r] : acc1[r];
        float key = __uint_as_float((__float_as_uint(fb) & 0xFFFFFFC0u) | tu);
        m2[k] = fmed3(key, m1[k], m2[k]);   // 2nd-max of {key,m1,m2}
        m1[k] = fmaxf(m1[k], key);
        Zs[k] += fexp2(fb);
      }
    }
    bh = nh; bl = nl;
  }

  // decode indices from this lane's own keys (c local), then reduce
  int i1[8], i2[8];
#pragma unroll
  for (int k = 0; k < 8; ++k) {
    i1[k] = nb0 + (int)((__float_as_uint(m1[k]) & 63u) << 4) + c;
    i2[k] = nb0 + (int)((__float_as_uint(m2[k]) & 63u) << 4) + c;
  }

#pragma unroll
  for (int d = 1; d < 16; d <<= 1) {
#pragma unroll
    for (int k = 0; k < 8; ++k) {
      float om1 = __shfl_xor(m1[k], d);
      float om2 = __shfl_xor(m2[k], d);
      float oZ = __shfl_xor(Zs[k], d);
      int oi1 = __shfl_xor(i1[k], d);
      int oi2 = __shfl_xor(i2[k], d);
      bool c1 = om1 > m1[k];
      float lm = c1 ? m1[k] : om1;
      int li = c1 ? i1[k] : oi1;
      float nm1 = c1 ? om1 : m1[k];
      int ni1 = c1 ? oi1 : i1[k];
      bool cb = om2 > m2[k];
      float mm2 = cb ? om2 : m2[k];
      int mi2 = cb ? oi2 : i2[k];
      bool c3 = mm2 > lm;
      m1[k] = nm1; i1[k] = ni1;
      m2[k] = c3 ? mm2 : lm;
      i2[k] = c3 ? mi2 : li;
      Zs[k] += oZ;
    }
  }

#pragma unroll
  for (int k = 0; k < 8; ++k) {
    if (c == k) {
      const int g = k >> 2, r = k & 3;
      const int t = rowbase + g * 16 + q * 4 + r;
      const int p = blockIdx.y * T + t;
      pm1[p] = m1[k]; pm2[p] = m2[k]; pZ[p] = Zs[k];
      pi1[p] = i1[k]; pi2[p] = i2[k];
    }
  }
}

// --- fused tail: 1024 uniform blocks. Each: (a) self-compute c2 slice in
//     LDS; (b) pass2 sweep; (c) merge/refine/output for 8 rows; (d) last
//     finished block computes final scalars (device-scope counter). ---
__global__ __launch_bounds__(256, 4) void k_tail(
    const short* __restrict__ ehl, const short* __restrict__ zhl,
    const float* __restrict__ pm1, const float* __restrict__ pm2,
    const float* __restrict__ pZ, const int* __restrict__ pi1,
    const int* __restrict__ pi2, const float* __restrict__ zf,
    const float* __restrict__ embn, const float* __restrict__ ses2,
    const float* __restrict__ a02, float* __restrict__ avg,
    float* __restrict__ scal, float* __restrict__ out) {
  const int bid = blockIdx.x;
  const int tid = threadIdx.x;
  __shared__ float red[256];
  __shared__ float sc2[1024];
  __shared__ unsigned sord;

  // ---------- (a) c2 slice for rows tb0..tb0+1023 ----------
  const int bx = bid & 127, by = bid >> 7;
  const int tb0 = by * (T / RS2);
  for (int i = tid; i < 1024; i += 256) {
    const int t = tb0 + i;
    float Z = 0.f;
    for (int s = 0; s < NS1; ++s) Z += pZ[s * T + t];
    sc2[i] = a02[t] - (flog2(Z) - 80.0f);
  }
  __syncthreads();

  // ---------- (b) pass 2 sweep ----------
  {
    const int lane = tid & 63, wv = tid >> 6;
    const int q = lane >> 4, c = lane & 15;
    const int cbase = bx * 128 + wv * 32;
    const int NT = (T / RS2) / 16;     // 64

    const s16x8* eg = (const s16x8*)ehl;
    const int atile = cbase >> 4;
    s16x8 ah0 = eg[atile * 128 + lane],       al0 = eg[atile * 128 + 64 + lane];
    s16x8 ah1 = eg[(atile + 1) * 128 + lane], al1 = eg[(atile + 1) * 128 + 64 + lane];

    f32x4 sg;                           // ses2 ~ const (consistent with pass1)
#pragma unroll
    for (int r = 0; r < 4; ++r) sg[r] = NS2F;

    float accP[8], accE[8];
#pragma unroll
    for (int k = 0; k < 8; ++k) { accP[k] = 0.f; accE[k] = 0.f; }

    const s16x8* zg = (const s16x8*)zhl;
    const int btile0 = tb0 >> 4;
    s16x8 bh = zg[btile0 * 128 + lane], bl = zg[btile0 * 128 + 64 + lane];
    float cc = sc2[c];

    for (int tile = 0; tile < NT; ++tile) {
      const int nx = (tile + 1 < NT) ? tile + 1 : tile;
      const int nidx = (btile0 + nx) * 128 + lane;
      s16x8 nh = zg[nidx], nl = zg[nidx + 64];            // prefetch (2x1KB)
      float ncc = sc2[nx * 16 + c];

      f32x4 acc0 = __builtin_amdgcn_mfma_f32_16x16x32_bf16(ah0, bh, sg, 0, 0, 0);
      f32x4 acc1 = __builtin_amdgcn_mfma_f32_16x16x32_bf16(ah1, bh, sg, 0, 0, 0);
      acc0 = __builtin_amdgcn_mfma_f32_16x16x32_bf16(al0, bh, acc0, 0, 0, 0);
      acc1 = __builtin_amdgcn_mfma_f32_16x16x32_bf16(al1, bh, acc1, 0, 0, 0);
      acc0 = __builtin_amdgcn_mfma_f32_16x16x32_bf16(ah0, bl, acc0, 0, 0, 0);
      acc1 = __builtin_amdgcn_mfma_f32_16x16x32_bf16(ah1, bl, acc1, 0, 0, 0);

#pragma unroll
      for (int g = 0; g < 2; ++g) {
#pragma unroll
        for (int r = 0; r < 4; ++r) {
          const int k = g * 4 + r;
          float dl = ((g == 0) ? acc0[r] : acc1[r]) + cc;  // fb - lse2 (<=0)
          float p = fexp2(dl);                              // underflow -> 0
          accP[k] += p;
          accE[k] = fmaf(p, dl, accE[k]);
        }
      }
      bh = nh; bl = nl; cc = ncc;
    }

    float etot = 0.f;
#pragma unroll
    for (int k = 0; k < 8; ++k) etot += accE[k];

#pragma unroll
    for (int d = 1; d < 16; d <<= 1) {
#pragma unroll
      for (int k = 0; k < 8; ++k) accP[k] += __shfl_xor(accP[k], d);
    }
#pragma unroll
    for (int k = 0; k < 8; ++k) {
      if (c == k) {
        const int g = k >> 2, r = k & 3;
        atomicAdd(&avg[cbase + g * 16 + q * 4 + r], accP[k]);
      }
    }
    red[tid] = etot;
    __syncthreads();
    for (int st = 128; st > 0; st >>= 1) {
      if (tid < st) red[tid] += red[tid + st];
      __syncthreads();
    }
    if (tid == 0) atomicAdd(&scal[0], red[0]);
    __syncthreads();
  }

  // ---------- (c) distributed merge/refine/output: rows bid*8..+8 ----------
  {
    const int rg = tid >> 5;            // row group 0..7
    const int cl = tid & 31;            // channel lane 0..31
    const int t = bid * 8 + rg;

    float m1v = -1e30f, m2v = -1e30f; int i1v = 0, i2v = 0;
    if (cl < 16) {                      // lane = split s
      const int p = cl * T + t;
      m1v = pm1[p]; m2v = pm2[p]; i1v = pi1[p]; i2v = pi2[p];
    }
#pragma unroll
    for (int d = 1; d < 32; d <<= 1) {  // butterfly over the 16 real lanes
      float om1 = __shfl_xor(m1v, d);
      float om2 = __shfl_xor(m2v, d);
      int oi1 = __shfl_xor(i1v, d);
      int oi2 = __shfl_xor(i2v, d);
      bool c1 = om1 > m1v;
      float lm = c1 ? m1v : om1;
      int li = c1 ? i1v : oi1;
      float nm1 = c1 ? om1 : m1v;
      int ni1 = c1 ? oi1 : i1v;
      bool cb = om2 > m2v;
      float mm2 = cb ? om2 : m2v;
      int mi2 = cb ? oi2 : i2v;
      bool c3 = mm2 > lm;
      m1v = nm1; i1v = ni1;
      m2v = c3 ? mm2 : lm;
      i2v = c3 ? mi2 : li;
    }
    // broadcast half-wave lane 0 for cross-lane consistency of bi
    const int src = (tid & 63) & 32;
    i1v = __shfl(i1v, src);
    i2v = __shfl(i2v, src);

    const float zv = zf[(size_t)t * ED + cl];
    float p1 = embn[(size_t)i1v * ED + cl] * zv;
    float p2 = embn[(size_t)i2v * ED + cl] * zv;
#pragma unroll
    for (int d = 1; d < 32; d <<= 1) {
      p1 += __shfl_xor(p1, d);
      p2 += __shfl_xor(p2, d);
    }
    const float a02t = a02[t];
    float fb1 = fmaf(K2, p1, a02t + ses2[i1v]);   // true ses2: exact rule
    float fb2 = fmaf(K2, p2, a02t + ses2[i2v]);
    int bi = (fb2 > fb1 || (fb2 == fb1 && i2v < i1v)) ? i2v : i1v;

    float qv = embn[(size_t)bi * ED + cl];
    float df = qv - zv;
    const int b = t >> 8, hw = t & 255;
    out[(size_t)b * (ED * 256) + cl * 256 + hw] = zv + (qv - zv);

    red[tid] = df * df;
    __syncthreads();
    for (int st = 128; st > 0; st >>= 1) {
      if (tid < st) red[tid] += red[tid + st];
      __syncthreads();
    }
    if (tid == 0) atomicAdd(&scal[1], red[0]);
  }

  // ---------- (d) last-block final scalar phase ----------
  __threadfence();                      // publish this block's atomics
  __syncthreads();
  if (tid == 0) sord = atomicAdd((unsigned*)&scal[2], 1u);
  __syncthreads();
  if (sord == NBLK_F - 1) {
    float s = 0.f;
    for (int i = tid; i < N_E; i += 256) {
      float a = __hip_atomic_load(&avg[i], __ATOMIC_RELAXED,
                                  __HIP_MEMORY_SCOPE_AGENT) * (1.0f / T);
      s += a * (flog2(a + 1e-5f) * LN2);
    }
    red[tid] = s;
    __syncthreads();
    for (int st = 128; st > 0; st >>= 1) {
      if (tid < st) red[tid] += red[tid + st];
      __syncthreads();
    }
    if (tid == 0) {
      float avg_entropy = -red[0];
      float se = __hip_atomic_load(&scal[0], __ATOMIC_RELAXED,
                                   __HIP_MEMORY_SCOPE_AGENT);
      float vqs = __hip_atomic_load(&scal[1], __ATOMIC_RELAXED,
                                    __HIP_MEMORY_SCOPE_AGENT);
      float sample_entropy = -(se * LN2) * (1.0f / T);
      float vq = vqs * (1.0f / (T * ED));
      out[T * ED + 0] = vq;
      out[T * ED + 1] = 0.25f * vq;
      out[T * ED + 2] = 0.1f * (sample_entropy - avg_entropy);
    }
  }
}

extern "C" void kernel_launch(void* const* d_in, const int* in_sizes, int n_in,
                              void* d_out, int out_size, void* d_ws, size_t ws_size,
                              hipStream_t stream) {
  const float* z = (const float*)d_in[0];
  const float* emb = (const float*)d_in[1];
  float* out = (float*)d_out;
  float* w = (float*)d_ws;

  float* embn = w;                          // 524288 f
  float* ses2 = embn + 524288;              // 16384
  float* zf   = ses2 + 16384;               // 262144
  float* a02  = zf + 262144;                // 8192
  short* ehl  = (short*)(a02 + 8192);       // 1048576 sh (524288 f)
  short* zhl  = ehl + 1048576;              // 524288 sh  (262144 f)
  float* pm1  = (float*)(zhl + 524288);     // NS1*T = 131072 f
  float* pm2  = pm1 + NS1 * T;              // 131072
  float* pZ   = pm2 + NS1 * T;              // 131072
  int*   pi1  = (int*)(pZ + NS1 * T);       // 131072
  int*   pi2  = pi1 + NS1 * T;              // 131072
  float* avg  = (float*)(pi2 + NS1 * T);    // 16384
  float* scal = avg + 16384;                // 4: sampE, vq, counter, pad

  k_prep<<<161, 256, 0, stream>>>(emb, z, embn, ses2, zf, a02, ehl, zhl,
                                  avg, scal);
  k_pass1<<<dim3(T / 128, NS1), 256, 0, stream>>>(ehl, zhl, a02,
                                                  pm1, pm2, pZ, pi1, pi2);
  k_tail<<<NBLK_F, 256, 0, stream>>>(ehl, zhl, pm1, pm2, pZ, pi1, pi2, zf,
                                     embn, ses2, a02, avg, scal, out);
}

// Round 15
// 178.972 us; speedup vs baseline: 1.4669x; 1.4669x over previous
//
#include <hip/hip_runtime.h>

// VQ-VAE vector quantize + losses, MI355X.
// T=8192 rows, N_E=16384 codes, D=32.
// R15: rebuilt from R11 (best verified, 181us) with only decomposable deltas:
//      - pass1 with ses2~=NS2F folded into MFMA C-bias (verified R13/R14)
//      - pass2 launched straight after pass1, self-computing its c2 slice
//        from pZ in LDS (merge off the critical path); grid exactly 1024,
//        NO fence/counter (R13/R14's fused tails stalled at 25% occupancy)
//      - merge (32 blocks, thread=row, no Z-scan needed now) + last-block
//        final (fence x32 only)
//      - prep zeroes avg/scal. 4 launches.

#define N_E 16384
#define ED 32
#define T 8192
#define NS1 16      // pass-1 code splits (1024 codes each)
#define RS2 8       // pass-2 row splits  (1024 rows each)

#define K2 288.53900817779268f    // 200 * log2(e)
#define NS2F -144.26950408889634f // -100 * log2(e)
#define LN2 0.6931471805599453f

typedef __attribute__((ext_vector_type(8))) short s16x8;
typedef __attribute__((ext_vector_type(4))) float f32x4;

__device__ __forceinline__ float fexp2(float x) { return __builtin_amdgcn_exp2f(x); }
__device__ __forceinline__ float flog2(float x) { return __builtin_amdgcn_logf(x); }
__device__ __forceinline__ float fmed3(float a, float b, float c) {
  return __builtin_amdgcn_fmed3f(a, b, c);
}

__device__ __forceinline__ unsigned short f2bf(float x) {
  unsigned u = __float_as_uint(x);
  unsigned r = (u + 0x7FFFu + ((u >> 16) & 1u)) >> 16;
  return (unsigned short)r;
}
__device__ __forceinline__ float bf2f(unsigned short h) {
  return __uint_as_float(((unsigned)h) << 16);
}

// exact fp32 dot of a streamed row with 8 resident float4s (by value)
__device__ __forceinline__ float dot32x(const float* __restrict__ p,
    float4 z0, float4 z1, float4 z2, float4 z3,
    float4 z4, float4 z5, float4 z6, float4 z7) {
  const float4* e = (const float4*)p;
  float a0 = 0.f, a1 = 0.f, a2 = 0.f, a3 = 0.f; float4 q;
  q = e[0]; a0 = fmaf(q.x, z0.x, a0); a0 = fmaf(q.y, z0.y, a0);
            a0 = fmaf(q.z, z0.z, a0); a0 = fmaf(q.w, z0.w, a0);
  q = e[1]; a1 = fmaf(q.x, z1.x, a1); a1 = fmaf(q.y, z1.y, a1);
            a1 = fmaf(q.z, z1.z, a1); a1 = fmaf(q.w, z1.w, a1);
  q = e[2]; a2 = fmaf(q.x, z2.x, a2); a2 = fmaf(q.y, z2.y, a2);
            a2 = fmaf(q.z, z2.z, a2); a2 = fmaf(q.w, z2.w, a2);
  q = e[3]; a3 = fmaf(q.x, z3.x, a3); a3 = fmaf(q.y, z3.y, a3);
            a3 = fmaf(q.z, z3.z, a3); a3 = fmaf(q.w, z3.w, a3);
  q = e[4]; a0 = fmaf(q.x, z4.x, a0); a0 = fmaf(q.y, z4.y, a0);
            a0 = fmaf(q.z, z4.z, a0); a0 = fmaf(q.w, z4.w, a0);
  q = e[5]; a1 = fmaf(q.x, z5.x, a1); a1 = fmaf(q.y, z5.y, a1);
            a1 = fmaf(q.z, z5.z, a1); a1 = fmaf(q.w, z5.w, a1);
  q = e[6]; a2 = fmaf(q.x, z6.x, a2); a2 = fmaf(q.y, z6.y, a2);
            a2 = fmaf(q.z, z6.z, a2); a2 = fmaf(q.w, z6.w, a2);
  q = e[7]; a3 = fmaf(q.x, z7.x, a3); a3 = fmaf(q.y, z7.y, a3);
            a3 = fmaf(q.z, z7.z, a3); a3 = fmaf(q.w, z7.w, a3);
  return (a0 + a1) + (a2 + a3);
}

// split 8 floats (scaled by sc) of row `row`, group g into hi/lo bf16 frags,
// stored TILE-MAJOR: dst[tile*128 + g*16 + c] (hi), +64 (lo); s16x8 units.
__device__ __forceinline__ void split_store_t(short* __restrict__ base,
    int row, int g, float4 va, float4 vb, float sc) {
  float f[8] = { va.x * sc, va.y * sc, va.z * sc, va.w * sc,
                 vb.x * sc, vb.y * sc, vb.z * sc, vb.w * sc };
  s16x8 H, L;
#pragma unroll
  for (int e = 0; e < 8; ++e) {
    unsigned short h = f2bf(f[e]);
    H[e] = (short)h;
    L[e] = (short)f2bf(f[e] - bf2f(h));
  }
  s16x8* p = (s16x8*)base;
  const int tile = row >> 4, c = row & 15;
  p[tile * 128 + g * 16 + c] = H;
  p[tile * 128 + 64 + g * 16 + c] = L;
}

// --- prep: blocks 0..63 emb rows; 64..95 z transpose; 96..160 zero avg/scal ---
__global__ __launch_bounds__(256) void k_prep(const float* __restrict__ emb,
    const float* __restrict__ z, float* __restrict__ embn,
    float* __restrict__ ses2, float* __restrict__ zf, float* __restrict__ a02,
    short* __restrict__ ehl, short* __restrict__ zhl, float* __restrict__ avg,
    float* __restrict__ scal) {
  if (blockIdx.x < 64) {
    int n = blockIdx.x * 256 + threadIdx.x;
    const float4* r4 = (const float4*)(emb + (size_t)n * ED);
    float4 v[8]; float s = 0.f;
#pragma unroll
    for (int j = 0; j < 8; ++j) {
      v[j] = r4[j];
      s = fmaf(v[j].x, v[j].x, s); s = fmaf(v[j].y, v[j].y, s);
      s = fmaf(v[j].z, v[j].z, s); s = fmaf(v[j].w, v[j].w, s);
    }
    float inv = 1.0f / fmaxf(sqrtf(s), 1e-12f);
    float s2 = 0.f;
    float4* o4 = (float4*)(embn + (size_t)n * ED);
#pragma unroll
    for (int j = 0; j < 8; ++j) {
      float4 w; w.x = v[j].x * inv; w.y = v[j].y * inv;
      w.z = v[j].z * inv; w.w = v[j].w * inv;
      o4[j] = w; v[j] = w;
      s2 = fmaf(w.x, w.x, s2); s2 = fmaf(w.y, w.y, s2);
      s2 = fmaf(w.z, w.z, s2); s2 = fmaf(w.w, w.w, s2);
    }
    ses2[n] = NS2F * s2;               // true value, for the exact refine
#pragma unroll
    for (int g = 0; g < 4; ++g)
      split_store_t(ehl, n, g, v[2 * g], v[2 * g + 1], 1.0f);
  } else if (blockIdx.x < 96) {
    int t = (blockIdx.x - 64) * 256 + threadIdx.x;
    int b = t >> 8, hw = t & 255;
    const float* base = z + (size_t)b * (ED * 256) + hw;
    float4 v[8]; float s = 0.f;
#pragma unroll
    for (int j = 0; j < 8; ++j) {
      float4 w;
      w.x = base[(4 * j + 0) * 256]; w.y = base[(4 * j + 1) * 256];
      w.z = base[(4 * j + 2) * 256]; w.w = base[(4 * j + 3) * 256];
      v[j] = w;
      s = fmaf(w.x, w.x, s); s = fmaf(w.y, w.y, s);
      s = fmaf(w.z, w.z, s); s = fmaf(w.w, w.w, s);
    }
    float inv = 1.0f / fmaxf(sqrtf(s), 1e-12f);
    float s2 = 0.f;
    float4* o4 = (float4*)(zf + (size_t)t * ED);
#pragma unroll
    for (int j = 0; j < 8; ++j) {
      float4 w; w.x = v[j].x * inv; w.y = v[j].y * inv;
      w.z = v[j].z * inv; w.w = v[j].w * inv;
      o4[j] = w; v[j] = w;
      s2 = fmaf(w.x, w.x, s2); s2 = fmaf(w.y, w.y, s2);
      s2 = fmaf(w.z, w.z, s2); s2 = fmaf(w.w, w.w, s2);
    }
    a02[t] = NS2F * s2;
#pragma unroll
    for (int g = 0; g < 4; ++g)
      split_store_t(zhl, t, g, v[2 * g], v[2 * g + 1], K2);
  } else if (blockIdx.x < 160) {
    avg[(blockIdx.x - 96) * 256 + threadIdx.x] = 0.f;
  } else {
    if (threadIdx.x < 4) scal[threadIdx.x] = 0.f;  // [0]=sampE [1]=vq [2]=cnt
  }
}

// --- pass 1: wave owns 32 rows, sweeps a 1024-code split in 16-code tiles.
//     C-bias = a02 + 80 + NS2F (ses2 folded); fb = acc. Top-2 via
//     mantissa-packed keys (tile idx in low 6 bits; med3+max only). ---
__global__ __launch_bounds__(256, 4) void k_pass1(
    const short* __restrict__ ehl, const short* __restrict__ zhl,
    const float* __restrict__ a02, float* __restrict__ pm1,
    float* __restrict__ pm2, float* __restrict__ pZ,
    int* __restrict__ pi1, int* __restrict__ pi2) {
  const int lane = threadIdx.x & 63, wv = threadIdx.x >> 6;
  const int q = lane >> 4, c = lane & 15;
  const int rowbase = blockIdx.x * 128 + wv * 32;
  const int nb0 = blockIdx.y * (N_E / NS1);
  const int NT = (N_E / NS1) / 16;  // 64

  const s16x8* zg = (const s16x8*)zhl;
  const int atile = rowbase >> 4;
  s16x8 ah0 = zg[atile * 128 + lane],       al0 = zg[atile * 128 + 64 + lane];
  s16x8 ah1 = zg[(atile + 1) * 128 + lane], al1 = zg[(atile + 1) * 128 + 64 + lane];

  f32x4 bias0, bias1;
#pragma unroll
  for (int r = 0; r < 4; ++r) {
    bias0[r] = a02[rowbase + q * 4 + r] + (80.0f + NS2F);
    bias1[r] = a02[rowbase + 16 + q * 4 + r] + (80.0f + NS2F);
  }

  float m1[8], m2[8], Zs[8];
#pragma unroll
  for (int k = 0; k < 8; ++k) { m1[k] = -1e30f; m2[k] = -1e30f; Zs[k] = 0.f; }

  const s16x8* eg = (const s16x8*)ehl;
  const int btile0 = nb0 >> 4;
  s16x8 bh = eg[btile0 * 128 + lane], bl = eg[btile0 * 128 + 64 + lane];

  for (int tile = 0; tile < NT; ++tile) {
    const int nx = (tile + 1 < NT) ? tile + 1 : tile;     // uniform
    const int nidx = (btile0 + nx) * 128 + lane;
    s16x8 nh = eg[nidx], nl = eg[nidx + 64];              // prefetch (2x1KB)

    f32x4 acc0 = __builtin_amdgcn_mfma_f32_16x16x32_bf16(ah0, bh, bias0, 0, 0, 0);
    f32x4 acc1 = __builtin_amdgcn_mfma_f32_16x16x32_bf16(ah1, bh, bias1, 0, 0, 0);
    acc0 = __builtin_amdgcn_mfma_f32_16x16x32_bf16(al0, bh, acc0, 0, 0, 0);
    acc1 = __builtin_amdgcn_mfma_f32_16x16x32_bf16(al1, bh, acc1, 0, 0, 0);
    acc0 = __builtin_amdgcn_mfma_f32_16x16x32_bf16(ah0, bl, acc0, 0, 0, 0);
    acc1 = __builtin_amdgcn_mfma_f32_16x16x32_bf16(ah1, bl, acc1, 0, 0, 0);

    const unsigned tu = (unsigned)tile;                   // uniform 6-bit idx
#pragma unroll
    for (int g = 0; g < 2; ++g) {
#pragma unroll
      for (int r = 0; r < 4; ++r) {
        const int k = g * 4 + r;
        float fb = (g == 0) ? acc0[r] : acc1[r];
        float key = __uint_as_float((__float_as_uint(fb) & 0xFFFFFFC0u) | tu);
        m2[k] = fmed3(key, m1[k], m2[k]);   // 2nd-max of {key,m1,m2}
        m1[k] = fmaxf(m1[k], key);
        Zs[k] += fexp2(fb);
      }
    }
    bh = nh; bl = nl;
  }

  // decode indices from this lane's own keys (c local), then reduce
  int i1[8], i2[8];
#pragma unroll
  for (int k = 0; k < 8; ++k) {
    i1[k] = nb0 + (int)((__float_as_uint(m1[k]) & 63u) << 4) + c;
    i2[k] = nb0 + (int)((__float_as_uint(m2[k]) & 63u) << 4) + c;
  }

#pragma unroll
  for (int d = 1; d < 16; d <<= 1) {
#pragma unroll
    for (int k = 0; k < 8; ++k) {
      float om1 = __shfl_xor(m1[k], d);
      float om2 = __shfl_xor(m2[k], d);
      float oZ = __shfl_xor(Zs[k], d);
      int oi1 = __shfl_xor(i1[k], d);
      int oi2 = __shfl_xor(i2[k], d);
      bool c1 = om1 > m1[k];
      float lm = c1 ? m1[k] : om1;
      int li = c1 ? i1[k] : oi1;
      float nm1 = c1 ? om1 : m1[k];
      int ni1 = c1 ? oi1 : i1[k];
      bool cb = om2 > m2[k];
      float mm2 = cb ? om2 : m2[k];
      int mi2 = cb ? oi2 : i2[k];
      bool c3 = mm2 > lm;
      m1[k] = nm1; i1[k] = ni1;
      m2[k] = c3 ? mm2 : lm;
      i2[k] = c3 ? mi2 : li;
      Zs[k] += oZ;
    }
  }

#pragma unroll
  for (int k = 0; k < 8; ++k) {
    if (c == k) {
      const int g = k >> 2, r = k & 3;
      const int t = rowbase + g * 16 + q * 4 + r;
      const int p = blockIdx.y * T + t;
      pm1[p] = m1[k]; pm2[p] = m2[k]; pZ[p] = Zs[k];
      pi1[p] = i1[k]; pi2[p] = i2[k];
    }
  }
}

// --- pass 2: 1024 uniform blocks; self-computed c2 slice in LDS; wave owns
//     32 codes, sweeps a 1024-row split. No fence/counter. ---
__global__ __launch_bounds__(256, 4) void k_pass2(
    const short* __restrict__ ehl, const short* __restrict__ zhl,
    const float* __restrict__ pZ, const float* __restrict__ a02,
    float* __restrict__ avg, float* __restrict__ scal) {
  const int bid = blockIdx.x;
  const int tid = threadIdx.x;
  __shared__ float red[256];
  __shared__ float sc2[1024];

  const int bx = bid & 127, by = bid >> 7;
  const int tb0 = by * (T / RS2);
  for (int i = tid; i < 1024; i += 256) {
    const int t = tb0 + i;
    float Z = 0.f;
    for (int s = 0; s < NS1; ++s) Z += pZ[s * T + t];
    sc2[i] = a02[t] - (flog2(Z) - 80.0f);
  }
  __syncthreads();

  const int lane = tid & 63, wv = tid >> 6;
  const int q = lane >> 4, c = lane & 15;
  const int cbase = bx * 128 + wv * 32;
  const int NT = (T / RS2) / 16;     // 64

  const s16x8* eg = (const s16x8*)ehl;
  const int atile = cbase >> 4;
  s16x8 ah0 = eg[atile * 128 + lane],       al0 = eg[atile * 128 + 64 + lane];
  s16x8 ah1 = eg[(atile + 1) * 128 + lane], al1 = eg[(atile + 1) * 128 + 64 + lane];

  f32x4 sg;                           // ses2 ~ const (consistent with pass1)
#pragma unroll
  for (int r = 0; r < 4; ++r) sg[r] = NS2F;

  float accP[8], accE[8];
#pragma unroll
  for (int k = 0; k < 8; ++k) { accP[k] = 0.f; accE[k] = 0.f; }

  const s16x8* zg = (const s16x8*)zhl;
  const int btile0 = tb0 >> 4;
  s16x8 bh = zg[btile0 * 128 + lane], bl = zg[btile0 * 128 + 64 + lane];
  float cc = sc2[c];

  for (int tile = 0; tile < NT; ++tile) {
    const int nx = (tile + 1 < NT) ? tile + 1 : tile;
    const int nidx = (btile0 + nx) * 128 + lane;
    s16x8 nh = zg[nidx], nl = zg[nidx + 64];              // prefetch (2x1KB)
    float ncc = sc2[nx * 16 + c];

    f32x4 acc0 = __builtin_amdgcn_mfma_f32_16x16x32_bf16(ah0, bh, sg, 0, 0, 0);
    f32x4 acc1 = __builtin_amdgcn_mfma_f32_16x16x32_bf16(ah1, bh, sg, 0, 0, 0);
    acc0 = __builtin_amdgcn_mfma_f32_16x16x32_bf16(al0, bh, acc0, 0, 0, 0);
    acc1 = __builtin_amdgcn_mfma_f32_16x16x32_bf16(al1, bh, acc1, 0, 0, 0);
    acc0 = __builtin_amdgcn_mfma_f32_16x16x32_bf16(ah0, bl, acc0, 0, 0, 0);
    acc1 = __builtin_amdgcn_mfma_f32_16x16x32_bf16(ah1, bl, acc1, 0, 0, 0);

#pragma unroll
    for (int g = 0; g < 2; ++g) {
#pragma unroll
      for (int r = 0; r < 4; ++r) {
        const int k = g * 4 + r;
        float dl = ((g == 0) ? acc0[r] : acc1[r]) + cc;  // fb - lse2 (<=0)
        float p = fexp2(dl);                              // underflow -> 0
        accP[k] += p;
        accE[k] = fmaf(p, dl, accE[k]);
      }
    }
    bh = nh; bl = nl; cc = ncc;
  }

  float etot = 0.f;
#pragma unroll
  for (int k = 0; k < 8; ++k) etot += accE[k];

#pragma unroll
  for (int d = 1; d < 16; d <<= 1) {
#pragma unroll
    for (int k = 0; k < 8; ++k) accP[k] += __shfl_xor(accP[k], d);
  }
#pragma unroll
  for (int k = 0; k < 8; ++k) {
    if (c == k) {
      const int g = k >> 2, r = k & 3;
      atomicAdd(&avg[cbase + g * 16 + q * 4 + r], accP[k]);
    }
  }
  red[tid] = etot;
  __syncthreads();
  for (int st = 128; st > 0; st >>= 1) {
    if (tid < st) red[tid] += red[tid + st];
    __syncthreads();
  }
  if (tid == 0) atomicAdd(&scal[0], red[0]);
}

// --- merge-final: 32 blocks, thread = row. Top-2 combine (no Z needed),
//     exact fp32 refine, vq sum + straight-through output. Last finished
//     block computes the final scalars (counter on scal[2], 32 fences). ---
__global__ __launch_bounds__(256) void k_mf(
    const float* __restrict__ pm1, const float* __restrict__ pm2,
    const int* __restrict__ pi1, const int* __restrict__ pi2,
    const float* __restrict__ zf, const float* __restrict__ embn,
    const float* __restrict__ ses2, const float* __restrict__ a02,
    float* __restrict__ avg, float* __restrict__ scal, float* __restrict__ out) {
  const int tid = threadIdx.x;
  const int t = blockIdx.x * 256 + tid;
  __shared__ float red[256];
  __shared__ unsigned sord;

  float m1 = -1e30f, m2 = -1e30f;
  int i1 = 0, i2 = 0;
  for (int s = 0; s < NS1; ++s) {
    const int p = s * T + t;
    float sm1 = pm1[p], sm2 = pm2[p];
    int si1 = pi1[p], si2 = pi2[p];
    bool c1 = sm1 > m1;
    float lm = c1 ? m1 : sm1;
    int li = c1 ? i1 : si1;
    float nm1 = c1 ? sm1 : m1;
    int ni1 = c1 ? si1 : i1;
    bool cb = sm2 > m2;
    float mm2 = cb ? sm2 : m2;
    int mi2 = cb ? si2 : i2;
    bool c3 = mm2 > lm;
    m1 = nm1; i1 = ni1;
    m2 = c3 ? mm2 : lm;
    i2 = c3 ? mi2 : li;
  }
  const float a02t = a02[t];

  const float4* zr4 = (const float4*)(zf + (size_t)t * ED);
  float4 z0 = zr4[0], z1 = zr4[1], z2 = zr4[2], z3 = zr4[3];
  float4 z4 = zr4[4], z5 = zr4[5], z6 = zr4[6], z7 = zr4[7];
  float d1 = dot32x(embn + (size_t)i1 * ED, z0, z1, z2, z3, z4, z5, z6, z7);
  float d2 = dot32x(embn + (size_t)i2 * ED, z0, z1, z2, z3, z4, z5, z6, z7);
  float fb1 = fmaf(K2, d1, a02t + ses2[i1]);   // true ses2: exact rule
  float fb2 = fmaf(K2, d2, a02t + ses2[i2]);
  int bi = (fb2 > fb1 || (fb2 == fb1 && i2 < i1)) ? i2 : i1;

  const int b = t >> 8, hw = t & 255;
  float* ob = out + (size_t)b * (ED * 256) + hw;
  float ss = 0.f;
  const float4* e4 = (const float4*)(embn + (size_t)bi * ED);
#pragma unroll
  for (int j = 0; j < 8; ++j) {
    float4 qv = e4[j];
    float4 zv = (j == 0) ? z0 : (j == 1) ? z1 : (j == 2) ? z2 : (j == 3) ? z3
              : (j == 4) ? z4 : (j == 5) ? z5 : (j == 6) ? z6 : z7;
    float df;
    df = qv.x - zv.x; ss = fmaf(df, df, ss); ob[(4 * j + 0) * 256] = zv.x + (qv.x - zv.x);
    df = qv.y - zv.y; ss = fmaf(df, df, ss); ob[(4 * j + 1) * 256] = zv.y + (qv.y - zv.y);
    df = qv.z - zv.z; ss = fmaf(df, df, ss); ob[(4 * j + 2) * 256] = zv.z + (qv.z - zv.z);
    df = qv.w - zv.w; ss = fmaf(df, df, ss); ob[(4 * j + 3) * 256] = zv.w + (qv.w - zv.w);
  }
  red[tid] = ss;
  __syncthreads();
  for (int st = 128; st > 0; st >>= 1) {
    if (tid < st) red[tid] += red[tid + st];
    __syncthreads();
  }
  if (tid == 0) atomicAdd(&scal[1], red[0]);

  // last-block final (avg/scal[0] were completed by the previous kernel)
  __threadfence();
  __syncthreads();
  if (tid == 0) sord = atomicAdd((unsigned*)&scal[2], 1u);
  __syncthreads();
  if (sord == 31) {
    float s = 0.f;
    for (int i = tid; i < N_E; i += 256) {
      float a = avg[i] * (1.0f / T);
      s += a * (flog2(a + 1e-5f) * LN2);
    }
    red[tid] = s;
    __syncthreads();
    for (int st = 128; st > 0; st >>= 1) {
      if (tid < st) red[tid] += red[tid + st];
      __syncthreads();
    }
    if (tid == 0) {
      float avg_entropy = -red[0];
      float se = scal[0];
      float vqs = __hip_atomic_load(&scal[1], __ATOMIC_RELAXED,
                                    __HIP_MEMORY_SCOPE_AGENT);
      float sample_entropy = -(se * LN2) * (1.0f / T);
      float vq = vqs * (1.0f / (T * ED));
      out[T * ED + 0] = vq;
      out[T * ED + 1] = 0.25f * vq;
      out[T * ED + 2] = 0.1f * (sample_entropy - avg_entropy);
    }
  }
}

extern "C" void kernel_launch(void* const* d_in, const int* in_sizes, int n_in,
                              void* d_out, int out_size, void* d_ws, size_t ws_size,
                              hipStream_t stream) {
  const float* z = (const float*)d_in[0];
  const float* emb = (const float*)d_in[1];
  float* out = (float*)d_out;
  float* w = (float*)d_ws;

  float* embn = w;                          // 524288 f
  float* ses2 = embn + 524288;              // 16384
  float* zf   = ses2 + 16384;               // 262144
  float* a02  = zf + 262144;                // 8192
  short* ehl  = (short*)(a02 + 8192);       // 1048576 sh (524288 f)
  short* zhl  = ehl + 1048576;              // 524288 sh  (262144 f)
  float* pm1  = (float*)(zhl + 524288);     // NS1*T = 131072 f
  float* pm2  = pm1 + NS1 * T;              // 131072
  float* pZ   = pm2 + NS1 * T;              // 131072
  int*   pi1  = (int*)(pZ + NS1 * T);       // 131072
  int*   pi2  = pi1 + NS1 * T;              // 131072
  float* avg  = (float*)(pi2 + NS1 * T);    // 16384
  float* scal = avg + 16384;                // 4: sampE, vq, counter, pad

  k_prep<<<161, 256, 0, stream>>>(emb, z, embn, ses2, zf, a02, ehl, zhl,
                                  avg, scal);
  k_pass1<<<dim3(T / 128, NS1), 256, 0, stream>>>(ehl, zhl, a02,
                                                  pm1, pm2, pZ, pi1, pi2);
  k_pass2<<<128 * RS2, 256, 0, stream>>>(ehl, zhl, pZ, a02, avg, scal);
  k_mf<<<32, 256, 0, stream>>>(pm1, pm2, pi1, pi2, zf, embn, ses2, a02,
                               avg, scal, out);
}